// Round 3
// baseline (2413.204 us; speedup 1.0000x reference)
//
#include <hip/hip_runtime.h>
#include <hip/hip_bf16.h>
#include <math.h>

#define D_MODEL 2048
#define VOCAB   32000
#define NTOK    8192
#define BM      128
#define BN      128
#define BKB     128               // K-tile in BYTES (= 128 fp8 elems)
#define BK      32                // fallback f32 path
#define LDK     (BK + 8)
#define MTILES  (NTOK / BM)       // 64
#define NTILES  (VOCAB / BN)      // 250
#define NCHUNK  (VOCAB / 64)      // 500

typedef __attribute__((ext_vector_type(8))) short  frag8;   // bf16 fallback
typedef __attribute__((ext_vector_type(4))) float  f32x4;
typedef __attribute__((ext_vector_type(4))) int    i32x4;
typedef __attribute__((ext_vector_type(8))) int    i32x8;

// ---------------- helpers ----------------

__device__ inline void g2l16(const void* g, void* l) {
    __builtin_amdgcn_global_load_lds(
        (const __attribute__((address_space(1))) unsigned int*)g,
        (__attribute__((address_space(3))) unsigned int*)l,
        16, 0, 0);
}

// pack two fp32 -> two bf16 (truncation), fallback path
__device__ inline unsigned pack_bf16(float x, float y) {
    union { float f; unsigned u; } a, b;
    a.f = x; b.f = y;
    return __builtin_amdgcn_perm(b.u, a.u, 0x07060302u);
}

// ---------------- fp32 -> fp8 e4m3 conversion (HW RNE via v_cvt_pk_fp8_f32) ----------------

__global__ void cvt_fp8_kernel(const float* __restrict__ src, unsigned char* __restrict__ dst) {
    size_t i = (size_t)blockIdx.x * 256 + threadIdx.x;   // one uint2 (8 fp8) per thread
    float4 v0 = ((const float4*)src)[2 * i];
    float4 v1 = ((const float4*)src)[2 * i + 1];
    int lo = 0, hi = 0;
    lo = __builtin_amdgcn_cvt_pk_fp8_f32(v0.x, v0.y, lo, 0);
    lo = __builtin_amdgcn_cvt_pk_fp8_f32(v0.z, v0.w, lo, 1);
    hi = __builtin_amdgcn_cvt_pk_fp8_f32(v1.x, v1.y, hi, 0);
    hi = __builtin_amdgcn_cvt_pk_fp8_f32(v1.z, v1.w, hi, 1);
    uint2 o = { (unsigned)lo, (unsigned)hi };
    ((uint2*)dst)[i] = o;
}

// ---------------- main GEMM+LSE: fp8 MX (scale=1), 16x16x128, swizzled LDS ----------------
//
// LDS layout: row r (128 B) split into 8 x 16B chunks; logical chunk j stored at
// position j ^ (r&7). global_load_lds dest stays wave-uniform+lane*16; the per-lane
// GLOBAL src address is permuted to compensate. Fragment reads: logical chunks
// 2q (lo) and 2q+1 (hi) -> positions plo = (2q)^(c&7), plo^1. Spreads same-q lanes
// over 8 bank groups (vs 4 naive) -> ~2x LDS read throughput.

__global__ __launch_bounds__(256)
void gemm_lse_fp8(const unsigned char* __restrict__ Hq, const unsigned char* __restrict__ Wq,
                  float* __restrict__ partials) {
    __shared__ unsigned char As[BM * BKB];   // 16 KB
    __shared__ unsigned char Bs[BN * BKB];   // 16 KB

    const int bid   = blockIdx.x;
    const int mtile = bid & (MTILES - 1);    // ntile-major for W L2 reuse
    const int ntile = bid >> 6;
    const int m0 = mtile * BM;
    const int n0 = ntile * BN;

    const int tid  = threadIdx.x;
    const int lane = tid & 63;
    const int w    = tid >> 6;
    const int wm   = (w >> 1) * 64;
    const int wn   = (w & 1)  * 64;
    const int q    = lane >> 4;
    const int c    = lane & 15;

    // staging: wave w covers rows [w*32, w*32+32); 4 calls x 8 rows per matrix
    size_t aoff[4], boff[4];
    unsigned char* lds_a[4];
    unsigned char* lds_b[4];
    #pragma unroll
    for (int t = 0; t < 4; ++t) {
        int r    = w * 32 + t * 8 + (lane >> 3);
        int soff = ((lane & 7) ^ (r & 7)) * 16;        // permuted source chunk
        aoff[t] = (size_t)(m0 + r) * D_MODEL + soff;
        boff[t] = (size_t)(n0 + r) * D_MODEL + soff;
        lds_a[t] = As + (w * 32 + t * 8) * BKB;        // wave-uniform
        lds_b[t] = Bs + (w * 32 + t * 8) * BKB;
    }

    const int plo = (2 * q) ^ (c & 7);                  // 16B slot of frag low half

    f32x4 acc[4][4];
    const f32x4 zero = {0.f, 0.f, 0.f, 0.f};
    #pragma unroll
    for (int i = 0; i < 4; ++i)
        #pragma unroll
        for (int j = 0; j < 4; ++j) acc[i][j] = zero;

    for (int kt = 0; kt < D_MODEL / BKB; ++kt) {
        const int k0 = kt * BKB;
        #pragma unroll
        for (int t = 0; t < 4; ++t) g2l16(Hq + aoff[t] + k0, lds_a[t]);
        #pragma unroll
        for (int t = 0; t < 4; ++t) g2l16(Wq + boff[t] + k0, lds_b[t]);
        __syncthreads();   // drains vmcnt -> LDS populated

        union Frag { i32x8 v; i32x4 h[2]; };
        i32x8 a8[4], b8[4];
        #pragma unroll
        for (int t = 0; t < 4; ++t) {
            const unsigned char* pa = As + (wm + t * 16 + c) * BKB;
            Frag f;
            f.h[0] = *(const i32x4*)(pa + plo * 16);
            f.h[1] = *(const i32x4*)(pa + (plo ^ 1) * 16);
            a8[t] = f.v;
        }
        #pragma unroll
        for (int t = 0; t < 4; ++t) {
            const unsigned char* pb = Bs + (wn + t * 16 + c) * BKB;
            Frag f;
            f.h[0] = *(const i32x4*)(pb + plo * 16);
            f.h[1] = *(const i32x4*)(pb + (plo ^ 1) * 16);
            b8[t] = f.v;
        }

        #pragma unroll
        for (int tm = 0; tm < 4; ++tm)
            #pragma unroll
            for (int tn = 0; tn < 4; ++tn)
                acc[tm][tn] = __builtin_amdgcn_mfma_scale_f32_16x16x128_f8f6f4(
                    a8[tm], b8[tn], acc[tm][tn],
                    0, 0,                       // cbsz=fp8(e4m3), blgp=fp8(e4m3)
                    0, 0x7F7F7F7F,              // scale_a sel, scale_a = 1.0 (E8M0 127)
                    0, 0x7F7F7F7F);             // scale_b sel, scale_b = 1.0
        __syncthreads();
    }

    // epilogue: per-row max & sum(exp) over this wave's 64 columns
    // C/D layout (16x16, shape-determined): col = lane&15, row = (lane>>4)*4 + reg
    const int chunk = ntile * 2 + (w & 1);
    #pragma unroll
    for (int tm = 0; tm < 4; ++tm) {
        #pragma unroll
        for (int r = 0; r < 4; ++r) {
            float v0 = acc[tm][0][r], v1 = acc[tm][1][r];
            float v2 = acc[tm][2][r], v3 = acc[tm][3][r];
            float mx = fmaxf(fmaxf(v0, v1), fmaxf(v2, v3));
            #pragma unroll
            for (int mask = 1; mask <= 8; mask <<= 1)
                mx = fmaxf(mx, __shfl_xor(mx, mask, 64));
            float sm = __expf(v0 - mx) + __expf(v1 - mx)
                     + __expf(v2 - mx) + __expf(v3 - mx);
            #pragma unroll
            for (int mask = 1; mask <= 8; mask <<= 1)
                sm += __shfl_xor(sm, mask, 64);
            if (c == 0) {
                int row_g = m0 + wm + tm * 16 + q * 4 + r;
                float* p = partials + ((size_t)row_g * NCHUNK + chunk) * 2;
                p[0] = mx;
                p[1] = sm;
            }
        }
    }
}

// ---------------- fallback GEMM (fp32 in-flight bf16 pack) ----------------

__global__ __launch_bounds__(256, 2)
void gemm_lse_f32(const float* __restrict__ H, const float* __restrict__ W,
                  float* __restrict__ partials) {
    __shared__ unsigned short As[BM][LDK];
    __shared__ unsigned short Bs[BN][LDK];

    const int GM = 8;
    int bid   = blockIdx.x;
    int super = bid / (GM * NTILES);
    int rem   = bid % (GM * NTILES);
    int mtile = super * GM + (rem % GM);
    int ntile = rem / GM;

    const int m0 = mtile * BM;
    const int n0 = ntile * BN;

    const int tid  = threadIdx.x;
    const int lane = tid & 63;
    const int w    = tid >> 6;
    const int wm   = (w >> 1) * 64;
    const int wn   = (w & 1)  * 64;
    const int q    = lane >> 4;
    const int c    = lane & 15;

    f32x4 acc[4][4];
    const f32x4 zero = {0.f, 0.f, 0.f, 0.f};
    #pragma unroll
    for (int i = 0; i < 4; ++i)
        #pragma unroll
        for (int j = 0; j < 4; ++j) acc[i][j] = zero;

    for (int kt = 0; kt < D_MODEL / BK; ++kt) {
        const int k0 = kt * BK;
        #pragma unroll
        for (int s = 0; s < 4; ++s) {
            int i   = tid + s * 256;
            int row = i >> 3;
            int kq  = (i & 7) << 2;

            const float4* pa = (const float4*)(H + (size_t)(m0 + row) * D_MODEL + k0 + kq);
            float4 va = *pa;
            uint2 ba = { pack_bf16(va.x, va.y), pack_bf16(va.z, va.w) };
            *(uint2*)&As[row][kq] = ba;

            const float4* pb = (const float4*)(W + (size_t)(n0 + row) * D_MODEL + k0 + kq);
            float4 vb = *pb;
            uint2 bb = { pack_bf16(vb.x, vb.y), pack_bf16(vb.z, vb.w) };
            *(uint2*)&Bs[row][kq] = bb;
        }
        __syncthreads();

        frag8 af[4], bf[4];
        #pragma unroll
        for (int t = 0; t < 4; ++t)
            af[t] = *(const frag8*)&As[wm + t * 16 + c][q * 8];
        #pragma unroll
        for (int t = 0; t < 4; ++t)
            bf[t] = *(const frag8*)&Bs[wn + t * 16 + c][q * 8];

        #pragma unroll
        for (int tm = 0; tm < 4; ++tm)
            #pragma unroll
            for (int tn = 0; tn < 4; ++tn)
                acc[tm][tn] = __builtin_amdgcn_mfma_f32_16x16x32_bf16(
                    af[tm], bf[tn], acc[tm][tn], 0, 0, 0);
        __syncthreads();
    }

    const int chunk = ntile * 2 + (w & 1);
    #pragma unroll
    for (int tm = 0; tm < 4; ++tm) {
        #pragma unroll
        for (int r = 0; r < 4; ++r) {
            float v0 = acc[tm][0][r], v1 = acc[tm][1][r];
            float v2 = acc[tm][2][r], v3 = acc[tm][3][r];
            float mx = fmaxf(fmaxf(v0, v1), fmaxf(v2, v3));
            #pragma unroll
            for (int mask = 1; mask <= 8; mask <<= 1)
                mx = fmaxf(mx, __shfl_xor(mx, mask, 64));
            float sm = __expf(v0 - mx) + __expf(v1 - mx)
                     + __expf(v2 - mx) + __expf(v3 - mx);
            #pragma unroll
            for (int mask = 1; mask <= 8; mask <<= 1)
                sm += __shfl_xor(sm, mask, 64);
            if (c == 0) {
                int row_g = m0 + wm + tm * 16 + q * 4 + r;
                float* p = partials + ((size_t)row_g * NCHUNK + chunk) * 2;
                p[0] = mx;
                p[1] = sm;
            }
        }
    }
}

// ---------------- aux kernels ----------------

__global__ void tgt_kernel(const float* __restrict__ H, const float* __restrict__ W,
                           const int* __restrict__ targets,
                           float* __restrict__ tgt_logit, float* __restrict__ accum) {
    int token = blockIdx.x;
    int tid   = threadIdx.x;
    if (token == 0 && tid == 0) { accum[0] = 0.f; accum[1] = 0.f; }

    int t  = targets[token];
    int tt = (t == -100) ? 0 : t;
    const float4* h  = (const float4*)(H + (size_t)token * D_MODEL);
    const float4* wr = (const float4*)(W + (size_t)tt * D_MODEL);
    float p = 0.f;
    for (int j = tid; j < D_MODEL / 4; j += 256) {
        float4 a = h[j], b = wr[j];
        p += a.x * b.x + a.y * b.y + a.z * b.z + a.w * b.w;
    }
    #pragma unroll
    for (int mask = 1; mask < 64; mask <<= 1)
        p += __shfl_xor(p, mask, 64);

    __shared__ float lp[4];
    int lane = tid & 63, wid = tid >> 6;
    if (lane == 0) lp[wid] = p;
    __syncthreads();
    if (tid == 0) tgt_logit[token] = lp[0] + lp[1] + lp[2] + lp[3];
}

__device__ inline void lse_merge(float& m, float& s, float om, float os) {
    if (om > m) { s = s * __expf(m - om) + os; m = om; }
    else        { s += os * __expf(om - m); }
}

__global__ void reduce_kernel(const float* __restrict__ partials,
                              const float* __restrict__ tgt_logit,
                              const int* __restrict__ targets,
                              float* __restrict__ accum) {
    int token = blockIdx.x;
    int tid   = threadIdx.x;
    float m = -INFINITY, s = 0.f;
    for (int ch = tid; ch < NCHUNK; ch += 256) {
        const float* p = partials + ((size_t)token * NCHUNK + ch) * 2;
        lse_merge(m, s, p[0], p[1]);
    }
    #pragma unroll
    for (int mask = 1; mask < 64; mask <<= 1) {
        float om = __shfl_xor(m, mask, 64);
        float os = __shfl_xor(s, mask, 64);
        lse_merge(m, s, om, os);
    }
    __shared__ float lm[4], ls[4];
    int lane = tid & 63, wid = tid >> 6;
    if (lane == 0) { lm[wid] = m; ls[wid] = s; }
    __syncthreads();
    if (tid == 0) {
        for (int i = 1; i < 4; ++i) lse_merge(m, s, lm[i], ls[i]);
        float lse = m + __logf(s);
        int t = targets[token];
        if (t != -100) {
            atomicAdd(&accum[0], lse - tgt_logit[token]);
            atomicAdd(&accum[1], 1.0f);
        }
    }
}

__global__ void final_kernel(const float* __restrict__ accum, float* __restrict__ out) {
    float L = accum[0], C = accum[1];
    out[0] = (C > 0.f) ? (L / C) : 0.f;
}

// ---------------- launch ----------------

extern "C" void kernel_launch(void* const* d_in, const int* in_sizes, int n_in,
                              void* d_out, int out_size, void* d_ws, size_t ws_size,
                              hipStream_t stream) {
    (void)in_sizes; (void)n_in; (void)out_size;
    const float* H       = (const float*)d_in[0];   // [4,2048,2048]
    const int*   targets = (const int*)d_in[1];     // [8192]
    const float* W       = (const float*)d_in[2];   // [32000,2048]
    float*       out     = (float*)d_out;

    char* ws = (char*)d_ws;
    const size_t H8_BYTES   = (size_t)NTOK  * D_MODEL;           //  16 MB
    const size_t W8_BYTES   = (size_t)VOCAB * D_MODEL;           //  64 MB
    const size_t PART_BYTES = (size_t)NTOK * NCHUNK * 2 * 4;     //  32 MB
    const size_t NEED = H8_BYTES + W8_BYTES + PART_BYTES + (size_t)NTOK * 4 + 64;

    if (ws_size >= NEED) {
        unsigned char* Hq = (unsigned char*)ws;
        unsigned char* Wq = (unsigned char*)(ws + H8_BYTES);
        float* partials   = (float*)(ws + H8_BYTES + W8_BYTES);
        float* tgt_logit  = (float*)(ws + H8_BYTES + W8_BYTES + PART_BYTES);
        float* accum      = tgt_logit + NTOK;

        cvt_fp8_kernel<<<(NTOK  * D_MODEL / 8) / 256, 256, 0, stream>>>(H, Hq);
        cvt_fp8_kernel<<<(VOCAB * D_MODEL / 8) / 256, 256, 0, stream>>>(W, Wq);
        tgt_kernel<<<NTOK, 256, 0, stream>>>(H, W, targets, tgt_logit, accum);
        gemm_lse_fp8<<<MTILES * NTILES, 256, 0, stream>>>(Hq, Wq, partials);
        reduce_kernel<<<NTOK, 256, 0, stream>>>(partials, tgt_logit, targets, accum);
        final_kernel<<<1, 1, 0, stream>>>(accum, out);
    } else {
        float* partials  = (float*)ws;
        float* tgt_logit = (float*)(ws + PART_BYTES);
        float* accum     = tgt_logit + NTOK;

        gemm_lse_f32<<<MTILES * NTILES, 256, 0, stream>>>(H, W, partials);
        tgt_kernel<<<NTOK, 256, 0, stream>>>(H, W, targets, tgt_logit, accum);
        reduce_kernel<<<NTOK, 256, 0, stream>>>(partials, tgt_logit, targets, accum);
        final_kernel<<<1, 1, 0, stream>>>(accum, out);
    }
}

// Round 4
// 1180.781 us; speedup vs baseline: 2.0437x; 2.0437x over previous
//
#include <hip/hip_runtime.h>
#include <hip/hip_bf16.h>
#include <math.h>

#define D_MODEL 2048
#define VOCAB   32000
#define NTOK    8192
#define BM      128
#define BN      128
#define BKB     128               // K-tile in BYTES (= 128 fp8 elems)
#define BK      32                // fallback f32 path
#define LDK     (BK + 8)
#define MTILES  (NTOK / BM)       // 64
#define NTILES  (VOCAB / BN)      // 250
#define NCHUNK  (VOCAB / 64)      // 500

typedef __attribute__((ext_vector_type(8))) short  frag8;   // bf16 fallback
typedef __attribute__((ext_vector_type(4))) float  f32x4;
typedef __attribute__((ext_vector_type(4))) int    i32x4;
typedef __attribute__((ext_vector_type(8))) int    i32x8;

// ---------------- helpers ----------------

__device__ inline void g2l16(const void* g, void* l) {
    __builtin_amdgcn_global_load_lds(
        (const __attribute__((address_space(1))) unsigned int*)g,
        (__attribute__((address_space(3))) unsigned int*)l,
        16, 0, 0);
}

// pack two fp32 -> two bf16 (truncation), fallback path
__device__ inline unsigned pack_bf16(float x, float y) {
    union { float f; unsigned u; } a, b;
    a.f = x; b.f = y;
    return __builtin_amdgcn_perm(b.u, a.u, 0x07060302u);
}

// ---------------- fp32 -> fp8 e4m3 conversion (HW RNE via v_cvt_pk_fp8_f32) ----------------

__global__ void cvt_fp8_kernel(const float* __restrict__ src, unsigned char* __restrict__ dst) {
    size_t i = (size_t)blockIdx.x * 256 + threadIdx.x;   // one uint2 (8 fp8) per thread
    float4 v0 = ((const float4*)src)[2 * i];
    float4 v1 = ((const float4*)src)[2 * i + 1];
    int lo = 0, hi = 0;
    lo = __builtin_amdgcn_cvt_pk_fp8_f32(v0.x, v0.y, lo, 0);
    lo = __builtin_amdgcn_cvt_pk_fp8_f32(v0.z, v0.w, lo, 1);
    hi = __builtin_amdgcn_cvt_pk_fp8_f32(v1.x, v1.y, hi, 0);
    hi = __builtin_amdgcn_cvt_pk_fp8_f32(v1.z, v1.w, hi, 1);
    uint2 o = { (unsigned)lo, (unsigned)hi };
    ((uint2*)dst)[i] = o;
}

// ---------------- main GEMM+LSE: fp8 MX (scale=1), 16x16x128, swizzled LDS ----------------
//
// LDS layout: row r (128 B) split into 8 x 16B chunks; logical chunk j stored at
// position j ^ (r&7). global_load_lds dest stays wave-uniform+lane*16; the per-lane
// GLOBAL src address is permuted to compensate. Fragment reads: logical chunks
// 2q (lo) and 2q+1 (hi) -> positions plo = (2q)^(c&7), plo^1.
//
// R4 fixes vs R3: #pragma unroll 1 on the K-loop (unroll-induced live-range
// explosion caused 256-VGPR + scratch spills, occupancy 12%), and
// __launch_bounds__(256,3) to cap VGPRs at ~168 (3 blocks/CU).

__global__ __launch_bounds__(256, 3)
void gemm_lse_fp8(const unsigned char* __restrict__ Hq, const unsigned char* __restrict__ Wq,
                  float* __restrict__ partials) {
    __shared__ unsigned char As[BM * BKB];   // 16 KB
    __shared__ unsigned char Bs[BN * BKB];   // 16 KB

    const int bid   = blockIdx.x;
    const int mtile = bid & (MTILES - 1);    // ntile-major for W L2 reuse
    const int ntile = bid >> 6;
    const int m0 = mtile * BM;
    const int n0 = ntile * BN;

    const int tid  = threadIdx.x;
    const int lane = tid & 63;
    const int w    = tid >> 6;
    const int wm   = (w >> 1) * 64;
    const int wn   = (w & 1)  * 64;
    const int q    = lane >> 4;
    const int c    = lane & 15;

    // staging: wave w covers rows [w*32, w*32+32); 4 calls x 8 rows per matrix
    const int srow = w * 32 + (lane >> 3);                 // + t*8
    const int soff = ((lane & 7) ^ (srow & 7)) * 16;       // permuted source chunk
    const unsigned char* gA = Hq + (size_t)(m0 + srow) * D_MODEL + soff;
    const unsigned char* gB = Wq + (size_t)(n0 + srow) * D_MODEL + soff;
    unsigned char* lA = As + (w * 32) * BKB;               // wave-uniform
    unsigned char* lB = Bs + (w * 32) * BKB;

    const int plo = (2 * q) ^ (c & 7);                      // 16B slot of frag low half

    f32x4 acc[4][4];
    const f32x4 zero = {0.f, 0.f, 0.f, 0.f};
    #pragma unroll
    for (int i = 0; i < 4; ++i)
        #pragma unroll
        for (int j = 0; j < 4; ++j) acc[i][j] = zero;

    #pragma unroll 1
    for (int kt = 0; kt < D_MODEL / BKB; ++kt) {
        const size_t k0 = (size_t)kt * BKB;
        #pragma unroll
        for (int t = 0; t < 4; ++t)
            g2l16(gA + k0 + (size_t)(t * 8) * D_MODEL, lA + t * 8 * BKB);
        #pragma unroll
        for (int t = 0; t < 4; ++t)
            g2l16(gB + k0 + (size_t)(t * 8) * D_MODEL, lB + t * 8 * BKB);
        __syncthreads();   // drains vmcnt -> LDS populated

        union Frag { i32x8 v; i32x4 h[2]; };
        i32x8 a8[4], b8[4];
        #pragma unroll
        for (int t = 0; t < 4; ++t) {
            const unsigned char* pa = As + (wm + t * 16 + c) * BKB;
            Frag f;
            f.h[0] = *(const i32x4*)(pa + plo * 16);
            f.h[1] = *(const i32x4*)(pa + (plo ^ 1) * 16);
            a8[t] = f.v;
        }
        #pragma unroll
        for (int t = 0; t < 4; ++t) {
            const unsigned char* pb = Bs + (wn + t * 16 + c) * BKB;
            Frag f;
            f.h[0] = *(const i32x4*)(pb + plo * 16);
            f.h[1] = *(const i32x4*)(pb + (plo ^ 1) * 16);
            b8[t] = f.v;
        }

        #pragma unroll
        for (int tm = 0; tm < 4; ++tm)
            #pragma unroll
            for (int tn = 0; tn < 4; ++tn)
                acc[tm][tn] = __builtin_amdgcn_mfma_scale_f32_16x16x128_f8f6f4(
                    a8[tm], b8[tn], acc[tm][tn],
                    0, 0,                       // cbsz=fp8(e4m3), blgp=fp8(e4m3)
                    0, 0x7F7F7F7F,              // scale_a = 1.0 (E8M0 127)
                    0, 0x7F7F7F7F);             // scale_b = 1.0
        __syncthreads();
    }

    // epilogue: per-row max & sum(exp) over this wave's 64 columns
    // C/D layout (16x16, shape-determined): col = lane&15, row = (lane>>4)*4 + reg
    const int chunk = ntile * 2 + (w & 1);
    #pragma unroll
    for (int tm = 0; tm < 4; ++tm) {
        #pragma unroll
        for (int r = 0; r < 4; ++r) {
            float v0 = acc[tm][0][r], v1 = acc[tm][1][r];
            float v2 = acc[tm][2][r], v3 = acc[tm][3][r];
            float mx = fmaxf(fmaxf(v0, v1), fmaxf(v2, v3));
            #pragma unroll
            for (int mask = 1; mask <= 8; mask <<= 1)
                mx = fmaxf(mx, __shfl_xor(mx, mask, 64));
            float sm = __expf(v0 - mx) + __expf(v1 - mx)
                     + __expf(v2 - mx) + __expf(v3 - mx);
            #pragma unroll
            for (int mask = 1; mask <= 8; mask <<= 1)
                sm += __shfl_xor(sm, mask, 64);
            if (c == 0) {
                int row_g = m0 + wm + tm * 16 + q * 4 + r;
                float* p = partials + ((size_t)row_g * NCHUNK + chunk) * 2;
                p[0] = mx;
                p[1] = sm;
            }
        }
    }
}

// ---------------- fallback GEMM (fp32 in-flight bf16 pack) ----------------

__global__ __launch_bounds__(256, 2)
void gemm_lse_f32(const float* __restrict__ H, const float* __restrict__ W,
                  float* __restrict__ partials) {
    __shared__ unsigned short As[BM][LDK];
    __shared__ unsigned short Bs[BN][LDK];

    const int GM = 8;
    int bid   = blockIdx.x;
    int super = bid / (GM * NTILES);
    int rem   = bid % (GM * NTILES);
    int mtile = super * GM + (rem % GM);
    int ntile = rem / GM;

    const int m0 = mtile * BM;
    const int n0 = ntile * BN;

    const int tid  = threadIdx.x;
    const int lane = tid & 63;
    const int w    = tid >> 6;
    const int wm   = (w >> 1) * 64;
    const int wn   = (w & 1)  * 64;
    const int q    = lane >> 4;
    const int c    = lane & 15;

    f32x4 acc[4][4];
    const f32x4 zero = {0.f, 0.f, 0.f, 0.f};
    #pragma unroll
    for (int i = 0; i < 4; ++i)
        #pragma unroll
        for (int j = 0; j < 4; ++j) acc[i][j] = zero;

    for (int kt = 0; kt < D_MODEL / BK; ++kt) {
        const int k0 = kt * BK;
        #pragma unroll
        for (int s = 0; s < 4; ++s) {
            int i   = tid + s * 256;
            int row = i >> 3;
            int kq  = (i & 7) << 2;

            const float4* pa = (const float4*)(H + (size_t)(m0 + row) * D_MODEL + k0 + kq);
            float4 va = *pa;
            uint2 ba = { pack_bf16(va.x, va.y), pack_bf16(va.z, va.w) };
            *(uint2*)&As[row][kq] = ba;

            const float4* pb = (const float4*)(W + (size_t)(n0 + row) * D_MODEL + k0 + kq);
            float4 vb = *pb;
            uint2 bb = { pack_bf16(vb.x, vb.y), pack_bf16(vb.z, vb.w) };
            *(uint2*)&Bs[row][kq] = bb;
        }
        __syncthreads();

        frag8 af[4], bf[4];
        #pragma unroll
        for (int t = 0; t < 4; ++t)
            af[t] = *(const frag8*)&As[wm + t * 16 + c][q * 8];
        #pragma unroll
        for (int t = 0; t < 4; ++t)
            bf[t] = *(const frag8*)&Bs[wn + t * 16 + c][q * 8];

        #pragma unroll
        for (int tm = 0; tm < 4; ++tm)
            #pragma unroll
            for (int tn = 0; tn < 4; ++tn)
                acc[tm][tn] = __builtin_amdgcn_mfma_f32_16x16x32_bf16(
                    af[tm], bf[tn], acc[tm][tn], 0, 0, 0);
        __syncthreads();
    }

    const int chunk = ntile * 2 + (w & 1);
    #pragma unroll
    for (int tm = 0; tm < 4; ++tm) {
        #pragma unroll
        for (int r = 0; r < 4; ++r) {
            float v0 = acc[tm][0][r], v1 = acc[tm][1][r];
            float v2 = acc[tm][2][r], v3 = acc[tm][3][r];
            float mx = fmaxf(fmaxf(v0, v1), fmaxf(v2, v3));
            #pragma unroll
            for (int mask = 1; mask <= 8; mask <<= 1)
                mx = fmaxf(mx, __shfl_xor(mx, mask, 64));
            float sm = __expf(v0 - mx) + __expf(v1 - mx)
                     + __expf(v2 - mx) + __expf(v3 - mx);
            #pragma unroll
            for (int mask = 1; mask <= 8; mask <<= 1)
                sm += __shfl_xor(sm, mask, 64);
            if (c == 0) {
                int row_g = m0 + wm + tm * 16 + q * 4 + r;
                float* p = partials + ((size_t)row_g * NCHUNK + chunk) * 2;
                p[0] = mx;
                p[1] = sm;
            }
        }
    }
}

// ---------------- aux kernels ----------------

__global__ void tgt_kernel(const float* __restrict__ H, const float* __restrict__ W,
                           const int* __restrict__ targets,
                           float* __restrict__ tgt_logit, float* __restrict__ accum) {
    int token = blockIdx.x;
    int tid   = threadIdx.x;
    if (token == 0 && tid == 0) { accum[0] = 0.f; accum[1] = 0.f; }

    int t  = targets[token];
    int tt = (t == -100) ? 0 : t;
    const float4* h  = (const float4*)(H + (size_t)token * D_MODEL);
    const float4* wr = (const float4*)(W + (size_t)tt * D_MODEL);
    float p = 0.f;
    for (int j = tid; j < D_MODEL / 4; j += 256) {
        float4 a = h[j], b = wr[j];
        p += a.x * b.x + a.y * b.y + a.z * b.z + a.w * b.w;
    }
    #pragma unroll
    for (int mask = 1; mask < 64; mask <<= 1)
        p += __shfl_xor(p, mask, 64);

    __shared__ float lp[4];
    int lane = tid & 63, wid = tid >> 6;
    if (lane == 0) lp[wid] = p;
    __syncthreads();
    if (tid == 0) tgt_logit[token] = lp[0] + lp[1] + lp[2] + lp[3];
}

__device__ inline void lse_merge(float& m, float& s, float om, float os) {
    if (om > m) { s = s * __expf(m - om) + os; m = om; }
    else        { s += os * __expf(om - m); }
}

__global__ void reduce_kernel(const float* __restrict__ partials,
                              const float* __restrict__ tgt_logit,
                              const int* __restrict__ targets,
                              float* __restrict__ accum) {
    int token = blockIdx.x;
    int tid   = threadIdx.x;
    float m = -INFINITY, s = 0.f;
    for (int ch = tid; ch < NCHUNK; ch += 256) {
        const float* p = partials + ((size_t)token * NCHUNK + ch) * 2;
        lse_merge(m, s, p[0], p[1]);
    }
    #pragma unroll
    for (int mask = 1; mask < 64; mask <<= 1) {
        float om = __shfl_xor(m, mask, 64);
        float os = __shfl_xor(s, mask, 64);
        lse_merge(m, s, om, os);
    }
    __shared__ float lm[4], ls[4];
    int lane = tid & 63, wid = tid >> 6;
    if (lane == 0) { lm[wid] = m; ls[wid] = s; }
    __syncthreads();
    if (tid == 0) {
        for (int i = 1; i < 4; ++i) lse_merge(m, s, lm[i], ls[i]);
        float lse = m + __logf(s);
        int t = targets[token];
        if (t != -100) {
            atomicAdd(&accum[0], lse - tgt_logit[token]);
            atomicAdd(&accum[1], 1.0f);
        }
    }
}

__global__ void final_kernel(const float* __restrict__ accum, float* __restrict__ out) {
    float L = accum[0], C = accum[1];
    out[0] = (C > 0.f) ? (L / C) : 0.f;
}

// ---------------- launch ----------------

extern "C" void kernel_launch(void* const* d_in, const int* in_sizes, int n_in,
                              void* d_out, int out_size, void* d_ws, size_t ws_size,
                              hipStream_t stream) {
    (void)in_sizes; (void)n_in; (void)out_size;
    const float* H       = (const float*)d_in[0];   // [4,2048,2048]
    const int*   targets = (const int*)d_in[1];     // [8192]
    const float* W       = (const float*)d_in[2];   // [32000,2048]
    float*       out     = (float*)d_out;

    char* ws = (char*)d_ws;
    const size_t H8_BYTES   = (size_t)NTOK  * D_MODEL;           //  16 MB
    const size_t W8_BYTES   = (size_t)VOCAB * D_MODEL;           //  64 MB
    const size_t PART_BYTES = (size_t)NTOK * NCHUNK * 2 * 4;     //  32 MB
    const size_t NEED = H8_BYTES + W8_BYTES + PART_BYTES + (size_t)NTOK * 4 + 64;

    if (ws_size >= NEED) {
        unsigned char* Hq = (unsigned char*)ws;
        unsigned char* Wq = (unsigned char*)(ws + H8_BYTES);
        float* partials   = (float*)(ws + H8_BYTES + W8_BYTES);
        float* tgt_logit  = (float*)(ws + H8_BYTES + W8_BYTES + PART_BYTES);
        float* accum      = tgt_logit + NTOK;

        cvt_fp8_kernel<<<(NTOK  * D_MODEL / 8) / 256, 256, 0, stream>>>(H, Hq);
        cvt_fp8_kernel<<<(VOCAB * D_MODEL / 8) / 256, 256, 0, stream>>>(W, Wq);
        tgt_kernel<<<NTOK, 256, 0, stream>>>(H, W, targets, tgt_logit, accum);
        gemm_lse_fp8<<<MTILES * NTILES, 256, 0, stream>>>(Hq, Wq, partials);
        reduce_kernel<<<NTOK, 256, 0, stream>>>(partials, tgt_logit, targets, accum);
        final_kernel<<<1, 1, 0, stream>>>(accum, out);
    } else {
        float* partials  = (float*)ws;
        float* tgt_logit = (float*)(ws + PART_BYTES);
        float* accum     = tgt_logit + NTOK;

        gemm_lse_f32<<<MTILES * NTILES, 256, 0, stream>>>(H, W, partials);
        tgt_kernel<<<NTOK, 256, 0, stream>>>(H, W, targets, tgt_logit, accum);
        reduce_kernel<<<NTOK, 256, 0, stream>>>(partials, tgt_logit, targets, accum);
        final_kernel<<<1, 1, 0, stream>>>(accum, out);
    }
}

// Round 5
// 975.070 us; speedup vs baseline: 2.4749x; 1.2110x over previous
//
#include <hip/hip_runtime.h>
#include <hip/hip_bf16.h>
#include <math.h>

#define D_MODEL 2048
#define VOCAB   32000
#define NTOK    8192
#define BM      128
#define BN      128
#define BKB     128               // K-tile in BYTES (= 128 fp8 elems)
#define BK      32                // fallback f32 path
#define LDK     (BK + 8)
#define MTILES  (NTOK / BM)       // 64
#define NTILES  (VOCAB / BN)      // 250
#define NCHUNK  (VOCAB / 64)      // 500

typedef __attribute__((ext_vector_type(8))) short  frag8;   // bf16 fallback
typedef __attribute__((ext_vector_type(4))) float  f32x4;
typedef __attribute__((ext_vector_type(4))) int    i32x4;
typedef __attribute__((ext_vector_type(8))) int    i32x8;

// ---------------- helpers ----------------

__device__ inline void g2l16(const void* g, void* l) {
    __builtin_amdgcn_global_load_lds(
        (const __attribute__((address_space(1))) unsigned int*)g,
        (__attribute__((address_space(3))) unsigned int*)l,
        16, 0, 0);
}

// pack two fp32 -> two bf16 (truncation), fallback path
__device__ inline unsigned pack_bf16(float x, float y) {
    union { float f; unsigned u; } a, b;
    a.f = x; b.f = y;
    return __builtin_amdgcn_perm(b.u, a.u, 0x07060302u);
}

// ---------------- fp32 -> fp8 e4m3 conversion (HW RNE via v_cvt_pk_fp8_f32) ----------------

__global__ void cvt_fp8_kernel(const float* __restrict__ src, unsigned char* __restrict__ dst) {
    size_t i = (size_t)blockIdx.x * 256 + threadIdx.x;   // one uint2 (8 fp8) per thread
    float4 v0 = ((const float4*)src)[2 * i];
    float4 v1 = ((const float4*)src)[2 * i + 1];
    int lo = 0, hi = 0;
    lo = __builtin_amdgcn_cvt_pk_fp8_f32(v0.x, v0.y, lo, 0);
    lo = __builtin_amdgcn_cvt_pk_fp8_f32(v0.z, v0.w, lo, 1);
    hi = __builtin_amdgcn_cvt_pk_fp8_f32(v1.x, v1.y, hi, 0);
    hi = __builtin_amdgcn_cvt_pk_fp8_f32(v1.z, v1.w, hi, 1);
    uint2 o = { (unsigned)lo, (unsigned)hi };
    ((uint2*)dst)[i] = o;
}

// ---------------- main GEMM+LSE: fp8 MX (scale=1), 16x16x128, swizzled LDS ----------------
//
// LDS layout: row r (128 B) split into 8 x 16B chunks; logical chunk j stored at
// position j ^ (r&7); global_load_lds src addresses permuted to compensate.
// #pragma unroll 1 on the K-loop + __launch_bounds__(256,3): without them the
// unroller software-pipelines 16 iterations -> 256 VGPR + scratch spills (R3).

__global__ __launch_bounds__(256, 3)
void gemm_lse_fp8(const unsigned char* __restrict__ Hq, const unsigned char* __restrict__ Wq,
                  float* __restrict__ partials) {
    __shared__ unsigned char As[BM * BKB];   // 16 KB
    __shared__ unsigned char Bs[BN * BKB];   // 16 KB

    const int bid   = blockIdx.x;
    const int mtile = bid & (MTILES - 1);    // ntile-major for W L2 reuse
    const int ntile = bid >> 6;
    const int m0 = mtile * BM;
    const int n0 = ntile * BN;

    const int tid  = threadIdx.x;
    const int lane = tid & 63;
    const int w    = tid >> 6;
    const int wm   = (w >> 1) * 64;
    const int wn   = (w & 1)  * 64;
    const int q    = lane >> 4;
    const int c    = lane & 15;

    // staging: wave w covers rows [w*32, w*32+32); 4 calls x 8 rows per matrix
    const int srow = w * 32 + (lane >> 3);                 // + t*8
    const int soff = ((lane & 7) ^ (srow & 7)) * 16;       // permuted source chunk
    const unsigned char* gA = Hq + (size_t)(m0 + srow) * D_MODEL + soff;
    const unsigned char* gB = Wq + (size_t)(n0 + srow) * D_MODEL + soff;
    unsigned char* lA = As + (w * 32) * BKB;               // wave-uniform
    unsigned char* lB = Bs + (w * 32) * BKB;

    const int plo = (2 * q) ^ (c & 7);                      // 16B slot of frag low half

    f32x4 acc[4][4];
    const f32x4 zero = {0.f, 0.f, 0.f, 0.f};
    #pragma unroll
    for (int i = 0; i < 4; ++i)
        #pragma unroll
        for (int j = 0; j < 4; ++j) acc[i][j] = zero;

    #pragma unroll 1
    for (int kt = 0; kt < D_MODEL / BKB; ++kt) {
        const size_t k0 = (size_t)kt * BKB;
        #pragma unroll
        for (int t = 0; t < 4; ++t)
            g2l16(gA + k0 + (size_t)(t * 8) * D_MODEL, lA + t * 8 * BKB);
        #pragma unroll
        for (int t = 0; t < 4; ++t)
            g2l16(gB + k0 + (size_t)(t * 8) * D_MODEL, lB + t * 8 * BKB);
        __syncthreads();   // drains vmcnt -> LDS populated

        union Frag { i32x8 v; i32x4 h[2]; };
        i32x8 a8[4], b8[4];
        #pragma unroll
        for (int t = 0; t < 4; ++t) {
            const unsigned char* pa = As + (wm + t * 16 + c) * BKB;
            Frag f;
            f.h[0] = *(const i32x4*)(pa + plo * 16);
            f.h[1] = *(const i32x4*)(pa + (plo ^ 1) * 16);
            a8[t] = f.v;
        }
        #pragma unroll
        for (int t = 0; t < 4; ++t) {
            const unsigned char* pb = Bs + (wn + t * 16 + c) * BKB;
            Frag f;
            f.h[0] = *(const i32x4*)(pb + plo * 16);
            f.h[1] = *(const i32x4*)(pb + (plo ^ 1) * 16);
            b8[t] = f.v;
        }

        #pragma unroll
        for (int tm = 0; tm < 4; ++tm)
            #pragma unroll
            for (int tn = 0; tn < 4; ++tn)
                acc[tm][tn] = __builtin_amdgcn_mfma_scale_f32_16x16x128_f8f6f4(
                    a8[tm], b8[tn], acc[tm][tn],
                    0, 0,                       // cbsz=fp8(e4m3), blgp=fp8(e4m3)
                    0, 0x7F7F7F7F,              // scale_a = 1.0 (E8M0 127)
                    0, 0x7F7F7F7F);             // scale_b = 1.0
        __syncthreads();
    }

    // epilogue: per-row max & sum(exp) over this wave's 64 columns
    // C/D layout (16x16, shape-determined): col = lane&15, row = (lane>>4)*4 + reg
    const int chunk = ntile * 2 + (w & 1);
    #pragma unroll
    for (int tm = 0; tm < 4; ++tm) {
        #pragma unroll
        for (int r = 0; r < 4; ++r) {
            float v0 = acc[tm][0][r], v1 = acc[tm][1][r];
            float v2 = acc[tm][2][r], v3 = acc[tm][3][r];
            float mx = fmaxf(fmaxf(v0, v1), fmaxf(v2, v3));
            #pragma unroll
            for (int mask = 1; mask <= 8; mask <<= 1)
                mx = fmaxf(mx, __shfl_xor(mx, mask, 64));
            float sm = __expf(v0 - mx) + __expf(v1 - mx)
                     + __expf(v2 - mx) + __expf(v3 - mx);
            #pragma unroll
            for (int mask = 1; mask <= 8; mask <<= 1)
                sm += __shfl_xor(sm, mask, 64);
            if (c == 0) {
                int row_g = m0 + wm + tm * 16 + q * 4 + r;
                float* p = partials + ((size_t)row_g * NCHUNK + chunk) * 2;
                p[0] = mx;
                p[1] = sm;
            }
        }
    }
}

// ---------------- fallback GEMM (fp32 in-flight bf16 pack) ----------------

__global__ __launch_bounds__(256, 2)
void gemm_lse_f32(const float* __restrict__ H, const float* __restrict__ W,
                  float* __restrict__ partials) {
    __shared__ unsigned short As[BM][LDK];
    __shared__ unsigned short Bs[BN][LDK];

    const int GM = 8;
    int bid   = blockIdx.x;
    int super = bid / (GM * NTILES);
    int rem   = bid % (GM * NTILES);
    int mtile = super * GM + (rem % GM);
    int ntile = rem / GM;

    const int m0 = mtile * BM;
    const int n0 = ntile * BN;

    const int tid  = threadIdx.x;
    const int lane = tid & 63;
    const int w    = tid >> 6;
    const int wm   = (w >> 1) * 64;
    const int wn   = (w & 1)  * 64;
    const int q    = lane >> 4;
    const int c    = lane & 15;

    f32x4 acc[4][4];
    const f32x4 zero = {0.f, 0.f, 0.f, 0.f};
    #pragma unroll
    for (int i = 0; i < 4; ++i)
        #pragma unroll
        for (int j = 0; j < 4; ++j) acc[i][j] = zero;

    for (int kt = 0; kt < D_MODEL / BK; ++kt) {
        const int k0 = kt * BK;
        #pragma unroll
        for (int s = 0; s < 4; ++s) {
            int i   = tid + s * 256;
            int row = i >> 3;
            int kq  = (i & 7) << 2;

            const float4* pa = (const float4*)(H + (size_t)(m0 + row) * D_MODEL + k0 + kq);
            float4 va = *pa;
            uint2 ba = { pack_bf16(va.x, va.y), pack_bf16(va.z, va.w) };
            *(uint2*)&As[row][kq] = ba;

            const float4* pb = (const float4*)(W + (size_t)(n0 + row) * D_MODEL + k0 + kq);
            float4 vb = *pb;
            uint2 bb = { pack_bf16(vb.x, vb.y), pack_bf16(vb.z, vb.w) };
            *(uint2*)&Bs[row][kq] = bb;
        }
        __syncthreads();

        frag8 af[4], bf[4];
        #pragma unroll
        for (int t = 0; t < 4; ++t)
            af[t] = *(const frag8*)&As[wm + t * 16 + c][q * 8];
        #pragma unroll
        for (int t = 0; t < 4; ++t)
            bf[t] = *(const frag8*)&Bs[wn + t * 16 + c][q * 8];

        #pragma unroll
        for (int tm = 0; tm < 4; ++tm)
            #pragma unroll
            for (int tn = 0; tn < 4; ++tn)
                acc[tm][tn] = __builtin_amdgcn_mfma_f32_16x16x32_bf16(
                    af[tm], bf[tn], acc[tm][tn], 0, 0, 0);
        __syncthreads();
    }

    const int chunk = ntile * 2 + (w & 1);
    #pragma unroll
    for (int tm = 0; tm < 4; ++tm) {
        #pragma unroll
        for (int r = 0; r < 4; ++r) {
            float v0 = acc[tm][0][r], v1 = acc[tm][1][r];
            float v2 = acc[tm][2][r], v3 = acc[tm][3][r];
            float mx = fmaxf(fmaxf(v0, v1), fmaxf(v2, v3));
            #pragma unroll
            for (int mask = 1; mask <= 8; mask <<= 1)
                mx = fmaxf(mx, __shfl_xor(mx, mask, 64));
            float sm = __expf(v0 - mx) + __expf(v1 - mx)
                     + __expf(v2 - mx) + __expf(v3 - mx);
            #pragma unroll
            for (int mask = 1; mask <= 8; mask <<= 1)
                sm += __shfl_xor(sm, mask, 64);
            if (c == 0) {
                int row_g = m0 + wm + tm * 16 + q * 4 + r;
                float* p = partials + ((size_t)row_g * NCHUNK + chunk) * 2;
                p[0] = mx;
                p[1] = sm;
            }
        }
    }
}

// ---------------- aux kernels (no global atomics anywhere) ----------------

// one WAVE per token: exact fp32 dot(h[n], w[target[n]])
__global__ __launch_bounds__(256)
void tgt_kernel(const float* __restrict__ H, const float* __restrict__ W,
                const int* __restrict__ targets, float* __restrict__ tgt_logit) {
    int token = blockIdx.x * 4 + (threadIdx.x >> 6);
    int lane  = threadIdx.x & 63;

    int t  = targets[token];
    int tt = (t == -100) ? 0 : t;
    const float4* h  = (const float4*)(H + (size_t)token * D_MODEL);
    const float4* wr = (const float4*)(W + (size_t)tt * D_MODEL);
    float p = 0.f;
    #pragma unroll
    for (int j = lane; j < D_MODEL / 4; j += 64) {
        float4 a = h[j], b = wr[j];
        p += a.x * b.x + a.y * b.y + a.z * b.z + a.w * b.w;
    }
    #pragma unroll
    for (int mask = 1; mask < 64; mask <<= 1)
        p += __shfl_xor(p, mask, 64);
    if (lane == 0) tgt_logit[token] = p;
}

__device__ inline void lse_merge(float& m, float& s, float om, float os) {
    if (om > m) { s = s * __expf(m - om) + os; m = om; }
    else        { s += os * __expf(om - m); }
}

// one WAVE per token: merge 500 (m,s) chunks -> nll[token]; no atomics
__global__ __launch_bounds__(256)
void reduce_kernel(const float* __restrict__ partials,
                   const float* __restrict__ tgt_logit,
                   const int* __restrict__ targets,
                   float* __restrict__ nll) {
    int token = blockIdx.x * 4 + (threadIdx.x >> 6);
    int lane  = threadIdx.x & 63;

    float m = -INFINITY, s = 0.f;
    const float* base = partials + (size_t)token * NCHUNK * 2;
    for (int ch = lane; ch < NCHUNK; ch += 64) {
        float2 p = ((const float2*)base)[ch];
        lse_merge(m, s, p.x, p.y);
    }
    #pragma unroll
    for (int mask = 1; mask < 64; mask <<= 1) {
        float om = __shfl_xor(m, mask, 64);
        float os = __shfl_xor(s, mask, 64);
        lse_merge(m, s, om, os);
    }
    if (lane == 0) {
        int t = targets[token];
        nll[token] = (t != -100) ? (m + __logf(s) - tgt_logit[token]) : 0.0f;
    }
}

// single block: sum nll + count valid, divide
__global__ __launch_bounds__(256)
void final_kernel(const float* __restrict__ nll, const int* __restrict__ targets,
                  float* __restrict__ out) {
    int tid = threadIdx.x;
    float sum = 0.f, cnt = 0.f;
    for (int i = tid; i < NTOK; i += 256) {
        sum += nll[i];
        cnt += (targets[i] != -100) ? 1.0f : 0.0f;
    }
    #pragma unroll
    for (int mask = 1; mask < 64; mask <<= 1) {
        sum += __shfl_xor(sum, mask, 64);
        cnt += __shfl_xor(cnt, mask, 64);
    }
    __shared__ float lsum[4], lcnt[4];
    int lane = tid & 63, wid = tid >> 6;
    if (lane == 0) { lsum[wid] = sum; lcnt[wid] = cnt; }
    __syncthreads();
    if (tid == 0) {
        float S = lsum[0] + lsum[1] + lsum[2] + lsum[3];
        float C = lcnt[0] + lcnt[1] + lcnt[2] + lcnt[3];
        out[0] = (C > 0.f) ? (S / C) : 0.f;
    }
}

// ---------------- launch ----------------

extern "C" void kernel_launch(void* const* d_in, const int* in_sizes, int n_in,
                              void* d_out, int out_size, void* d_ws, size_t ws_size,
                              hipStream_t stream) {
    (void)in_sizes; (void)n_in; (void)out_size;
    const float* H       = (const float*)d_in[0];   // [4,2048,2048]
    const int*   targets = (const int*)d_in[1];     // [8192]
    const float* W       = (const float*)d_in[2];   // [32000,2048]
    float*       out     = (float*)d_out;

    char* ws = (char*)d_ws;
    const size_t H8_BYTES   = (size_t)NTOK  * D_MODEL;           //  16 MB
    const size_t W8_BYTES   = (size_t)VOCAB * D_MODEL;           //  64 MB
    const size_t PART_BYTES = (size_t)NTOK * NCHUNK * 2 * 4;     //  32 MB
    const size_t NEED = H8_BYTES + W8_BYTES + PART_BYTES + (size_t)NTOK * 8 + 64;

    if (ws_size >= NEED) {
        unsigned char* Hq = (unsigned char*)ws;
        unsigned char* Wq = (unsigned char*)(ws + H8_BYTES);
        float* partials   = (float*)(ws + H8_BYTES + W8_BYTES);
        float* tgt_logit  = (float*)(ws + H8_BYTES + W8_BYTES + PART_BYTES);
        float* nll        = tgt_logit + NTOK;

        cvt_fp8_kernel<<<(NTOK  * D_MODEL / 8) / 256, 256, 0, stream>>>(H, Hq);
        cvt_fp8_kernel<<<(VOCAB * D_MODEL / 8) / 256, 256, 0, stream>>>(W, Wq);
        gemm_lse_fp8<<<MTILES * NTILES, 256, 0, stream>>>(Hq, Wq, partials);
        tgt_kernel<<<NTOK / 4, 256, 0, stream>>>(H, W, targets, tgt_logit);
        reduce_kernel<<<NTOK / 4, 256, 0, stream>>>(partials, tgt_logit, targets, nll);
        final_kernel<<<1, 256, 0, stream>>>(nll, targets, out);
    } else {
        float* partials  = (float*)ws;
        float* tgt_logit = (float*)(ws + PART_BYTES);
        float* nll       = tgt_logit + NTOK;

        gemm_lse_f32<<<MTILES * NTILES, 256, 0, stream>>>(H, W, partials);
        tgt_kernel<<<NTOK / 4, 256, 0, stream>>>(H, W, targets, tgt_logit);
        reduce_kernel<<<NTOK / 4, 256, 0, stream>>>(partials, tgt_logit, targets, nll);
        final_kernel<<<1, 256, 0, stream>>>(nll, targets, out);
    }
}